// Round 12
// baseline (56.142 us; speedup 1.0000x reference)
//
#include <hip/hip_runtime.h>

// RoutingLayer: capsule routing on MI355X (gfx950).
// n = 50000 nodes, D=128 = K=8 capsules x dd=16, M=20 neighbors, max_iter=3.
// Round 12 = round 11 (verified) + TWO independent nodes per wave (A/B):
// identical per-node lane math (2 dims/lane, asm DPP dot reduction,
// lane-parallel softmax, packed-f16 accumulation), registers duplicated.
// Rationale: r11 profiling showed latency-bound behavior (serial
// gather/LDS/exp chains, effective concurrency ~2-3); a second in-wave
// chain doubles ILP independent of occupancy. n = 6250*8 -> no tail.

#define D   128
#define K   8
#define DD  16
#define M   20

typedef _Float16 h2 __attribute__((ext_vector_type(2)));
typedef unsigned int u32;

__device__ __forceinline__ h2 pack_h2(float a, float b) {
    return __builtin_bit_cast(h2, __builtin_amdgcn_cvt_pkrtz(a, b));
}

// builtin (compiler-managed hazards) DPP add
#define DPPADD(x, ctrl) ((x) + __int_as_float(__builtin_amdgcn_update_dpp( \
        0, __float_as_int(x), (ctrl), 0xF, 0xF, false)))

__device__ __forceinline__ float red16_b(float x) {   // sum over 16-lane group
    x = DPPADD(x, 0xB1); x = DPPADD(x, 0x4E);
    x = DPPADD(x, 0x141); x = DPPADD(x, 0x140);
    return x;
}
__device__ __forceinline__ float red8_b(float x) {    // sum over 8-lane group
    x = DPPADD(x, 0xB1); x = DPPADD(x, 0x4E); x = DPPADD(x, 0x141);
    return x;
}

// 8 independent 8-lane sum reductions, 1 inst per DPP add; chains interleaved
// by 8 so every DPP reads a register written >=7 insts earlier (covers the
// VALU-write -> DPP-read wait states). Same proven pattern as r5/r10's X4.
#define RED8_X8(a0,a1,a2,a3,b0,b1,b2,b3) \
  asm volatile( \
    "s_nop 1\n\t" \
    "v_add_f32_dpp %0, %0, %0 quad_perm:[1,0,3,2] row_mask:0xf bank_mask:0xf\n\t" \
    "v_add_f32_dpp %1, %1, %1 quad_perm:[1,0,3,2] row_mask:0xf bank_mask:0xf\n\t" \
    "v_add_f32_dpp %2, %2, %2 quad_perm:[1,0,3,2] row_mask:0xf bank_mask:0xf\n\t" \
    "v_add_f32_dpp %3, %3, %3 quad_perm:[1,0,3,2] row_mask:0xf bank_mask:0xf\n\t" \
    "v_add_f32_dpp %4, %4, %4 quad_perm:[1,0,3,2] row_mask:0xf bank_mask:0xf\n\t" \
    "v_add_f32_dpp %5, %5, %5 quad_perm:[1,0,3,2] row_mask:0xf bank_mask:0xf\n\t" \
    "v_add_f32_dpp %6, %6, %6 quad_perm:[1,0,3,2] row_mask:0xf bank_mask:0xf\n\t" \
    "v_add_f32_dpp %7, %7, %7 quad_perm:[1,0,3,2] row_mask:0xf bank_mask:0xf\n\t" \
    "v_add_f32_dpp %0, %0, %0 quad_perm:[2,3,0,1] row_mask:0xf bank_mask:0xf\n\t" \
    "v_add_f32_dpp %1, %1, %1 quad_perm:[2,3,0,1] row_mask:0xf bank_mask:0xf\n\t" \
    "v_add_f32_dpp %2, %2, %2 quad_perm:[2,3,0,1] row_mask:0xf bank_mask:0xf\n\t" \
    "v_add_f32_dpp %3, %3, %3 quad_perm:[2,3,0,1] row_mask:0xf bank_mask:0xf\n\t" \
    "v_add_f32_dpp %4, %4, %4 quad_perm:[2,3,0,1] row_mask:0xf bank_mask:0xf\n\t" \
    "v_add_f32_dpp %5, %5, %5 quad_perm:[2,3,0,1] row_mask:0xf bank_mask:0xf\n\t" \
    "v_add_f32_dpp %6, %6, %6 quad_perm:[2,3,0,1] row_mask:0xf bank_mask:0xf\n\t" \
    "v_add_f32_dpp %7, %7, %7 quad_perm:[2,3,0,1] row_mask:0xf bank_mask:0xf\n\t" \
    "v_add_f32_dpp %0, %0, %0 row_half_mirror row_mask:0xf bank_mask:0xf\n\t" \
    "v_add_f32_dpp %1, %1, %1 row_half_mirror row_mask:0xf bank_mask:0xf\n\t" \
    "v_add_f32_dpp %2, %2, %2 row_half_mirror row_mask:0xf bank_mask:0xf\n\t" \
    "v_add_f32_dpp %3, %3, %3 row_half_mirror row_mask:0xf bank_mask:0xf\n\t" \
    "v_add_f32_dpp %4, %4, %4 row_half_mirror row_mask:0xf bank_mask:0xf\n\t" \
    "v_add_f32_dpp %5, %5, %5 row_half_mirror row_mask:0xf bank_mask:0xf\n\t" \
    "v_add_f32_dpp %6, %6, %6 row_half_mirror row_mask:0xf bank_mask:0xf\n\t" \
    "v_add_f32_dpp %7, %7, %7 row_half_mirror row_mask:0xf bank_mask:0xf" \
    : "+v"(a0), "+v"(a1), "+v"(a2), "+v"(a3), \
      "+v"(b0), "+v"(b1), "+v"(b2), "+v"(b3))

__device__ __forceinline__ float dot2(u32 za, h2 ub) {
#if __has_builtin(__builtin_amdgcn_fdot2)
    return __builtin_amdgcn_fdot2(__builtin_bit_cast(h2, za), ub, 0.0f, false);
#else
    h2 ah = __builtin_bit_cast(h2, za);
    return fmaf((float)ah.x, (float)ub.x, (float)ah.y * (float)ub.y);
#endif
}

// per-capsule L2 normalize into fp16 table, zero pad row at [total, total+D)
__global__ __launch_bounds__(256) void prenorm_kernel(const float* __restrict__ in,
                                                      _Float16* __restrict__ tab,
                                                      int total) {
    int i = blockIdx.x * 256 + threadIdx.x;
    float v = (i < total) ? in[i] : 0.0f;
    float s = red16_b(v * v);
    float inv = (s > 0.0f) ? rsqrtf(s) : 0.0f;
    if (i < total + D) tab[i] = (_Float16)(v * inv);
}

// ---- 2-node-per-wave routing (PRE path) ----
__global__ __launch_bounds__(256) void routing2_kernel(
    const _Float16* __restrict__ tab,  // [(n+1)*128] normalized fp16, row n = 0
    const int*      __restrict__ nbr,  // [n*20]
    const int*      __restrict__ maxit_p,
    float*          __restrict__ out,  // [n,128] fp32
    int n)
{
    const int t  = threadIdx.x;
    const int wv = t >> 6;                 // wave slot in block (0..3)
    const int l  = t & 63;                 // lane; owns dims (2l, 2l+1)
    const int myk  = l >> 3;               // capsule 0..7 (8 lanes each)
    const int nodeA = blockIdx.x * 8 + wv * 2;
    const int nodeB = nodeA + 1;
    if (nodeB >= n + 1) return;            // never taken for n=50000 (6250*8)
    const int max_iter = maxit_p[0];
    const int nuA = __builtin_amdgcn_readfirstlane(nodeA);
    const int nuB = __builtin_amdgcn_readfirstlane(nodeB);
    const int sA = wv * 2, sB = wv * 2 + 1;

    __shared__ float p_lds[8][M][K];       // logits (f32)
    __shared__ u32   w_lds[8][M][K];       // packed h2{w,w} weights

    // neighbor ids via scalar pipe (uniform addresses)
    int idsA[M], idsB[M];
    {
        const int* ra = nbr + nuA * M;
        const int* rb = nbr + nuB * M;
        #pragma unroll
        for (int mm = 0; mm < M; ++mm) {
            idsA[mm] = ra[mm] + nuA * 5;   // in [0,n]; row n is zeros
            idsB[mm] = rb[mm] + nuB * 5;
        }
    }

    const u32* t32 = (const u32*)tab;
    h2 xhA = __builtin_bit_cast(h2, t32[(size_t)nuA * (D / 2) + l]);
    h2 xhB = __builtin_bit_cast(h2, t32[(size_t)nuB * (D / 2) + l]);

    u32 zA[M], zB[M];
    #pragma unroll
    for (int mm = 0; mm < M; ++mm) {
        zA[mm] = t32[(size_t)idsA[mm] * (D / 2) + l];
        zB[mm] = t32[(size_t)idsB[mm] * (D / 2) + l];
    }

    // ---- iteration 0: u = x + 0.125 * sum_m z ----
    const h2 kEighth = pack_h2(0.125f, 0.125f);
    h2 uA = xhA, uB = xhB;
    #pragma unroll
    for (int mm = 0; mm < M; ++mm) {
        uA = __builtin_bit_cast(h2, zA[mm]) * kEighth + uA;   // v_pk_fma_f16
        uB = __builtin_bit_cast(h2, zB[mm]) * kEighth + uB;
    }
    if (max_iter > 1) {
        float sa = red8_b(dot2(__builtin_bit_cast(u32, uA), uA));
        float sb = red8_b(dot2(__builtin_bit_cast(u32, uB), uB));
        float ia = (sa > 0.0f) ? rsqrtf(sa) : 0.0f;
        float ib = (sb > 0.0f) ? rsqrtf(sb) : 0.0f;
        uA = uA * pack_h2(ia, ia);
        uB = uB * pack_h2(ib, ib);
    }

    // ---- iterations 1..max_iter-1 ----
    for (int it = 1; it < max_iter; ++it) {
        // phase 1: capsule dots -> p_lds (8 interleaved asm DPP chains)
        #pragma unroll
        for (int mm = 0; mm < M; mm += 4) {
            float a0 = dot2(zA[mm + 0], uA);
            float a1 = dot2(zA[mm + 1], uA);
            float a2 = dot2(zA[mm + 2], uA);
            float a3 = dot2(zA[mm + 3], uA);
            float b0 = dot2(zB[mm + 0], uB);
            float b1 = dot2(zB[mm + 1], uB);
            float b2 = dot2(zB[mm + 2], uB);
            float b3 = dot2(zB[mm + 3], uB);
            RED8_X8(a0, a1, a2, a3, b0, b1, b2, b3);
            if ((l & 7) == 0) {
                p_lds[sA][mm + 0][myk] = a0;
                p_lds[sA][mm + 1][myk] = a1;
                p_lds[sA][mm + 2][myk] = a2;
                p_lds[sA][mm + 3][myk] = a3;
                p_lds[sB][mm + 0][myk] = b0;
                p_lds[sB][mm + 1][myk] = b1;
                p_lds[sB][mm + 2][myk] = b2;
                p_lds[sB][mm + 3][myk] = b3;
            }
        }
        __builtin_amdgcn_wave_barrier();

        // phase 2: lane-parallel softmax for both nodes (interleaved chains).
        // Lane l handles (m = base + (l>>3), k = l&7); |p|<=1 -> no max-sub.
        // Clamped lanes recompute the m=M-1 value -> unconditional store safe.
        #pragma unroll
        for (int base = 0; base < M; base += 8) {
            int mm = base + (l >> 3);
            int mc = (mm < M) ? mm : (M - 1);
            float eA = __expf(p_lds[sA][mc][l & 7]);
            float eB = __expf(p_lds[sB][mc][l & 7]);
            float SA_ = red8_b(eA);
            float SB_ = red8_b(eB);
            float wA = eA * __builtin_amdgcn_rcpf(SA_);
            float wB = eB * __builtin_amdgcn_rcpf(SB_);
            w_lds[sA][mc][l & 7] = __builtin_bit_cast(u32, pack_h2(wA, wA));
            w_lds[sB][mc][l & 7] = __builtin_bit_cast(u32, pack_h2(wB, wB));
        }
        __builtin_amdgcn_wave_barrier();

        // phase 3: PV accumulate, packed f16
        h2 unA = xhA, unB = xhB;
        #pragma unroll
        for (int mm = 0; mm < M; ++mm) {
            h2 wa = __builtin_bit_cast(h2, w_lds[sA][mm][myk]);
            h2 wb = __builtin_bit_cast(h2, w_lds[sB][mm][myk]);
            unA = __builtin_bit_cast(h2, zA[mm]) * wa + unA;
            unB = __builtin_bit_cast(h2, zB[mm]) * wb + unB;
        }
        uA = unA; uB = unB;
        if (it < max_iter - 1) {
            float sa = red8_b(dot2(__builtin_bit_cast(u32, uA), uA));
            float sb = red8_b(dot2(__builtin_bit_cast(u32, uB), uB));
            float ia = (sa > 0.0f) ? rsqrtf(sa) : 0.0f;
            float ib = (sb > 0.0f) ? rsqrtf(sb) : 0.0f;
            uA = uA * pack_h2(ia, ia);
            uB = uB * pack_h2(ib, ib);
        }
        __builtin_amdgcn_wave_barrier();
    }

    float2* o2 = (float2*)out;
    o2[(size_t)nodeA * (D / 2) + l] = make_float2((float)uA.x, (float)uA.y);
    o2[(size_t)nodeB * (D / 2) + l] = make_float2((float)uB.x, (float)uB.y);
}

// ---- fallback (!PRE): r11 verified 1-node/wave kernel, normalize in-register ----
__global__ __launch_bounds__(256) void routing1_raw_kernel(
    const float* __restrict__ raw,
    const int*   __restrict__ nbr,
    const int*   __restrict__ maxit_p,
    float*       __restrict__ out,
    int n)
{
    const int t  = threadIdx.x;
    const int wv = t >> 6;
    const int l  = t & 63;
    const int node = blockIdx.x * 4 + wv;
    const int myk  = l >> 3;
    if (node >= n) return;
    const int max_iter = maxit_p[0];
    const int nodeu = __builtin_amdgcn_readfirstlane(node);

    __shared__ float p_lds[4][M][K];
    __shared__ u32   w_lds[4][M][K];

    int ids[M];
    {
        const int* nrow = nbr + nodeu * M;
        #pragma unroll
        for (int mm = 0; mm < M; ++mm) ids[mm] = nrow[mm] + nodeu * 5;
    }

    u32 z[M];
    h2  xh;
    {
        const float2* r2 = (const float2*)raw;
        float2 x0 = r2[(size_t)nodeu * (D / 2) + l];
        float s = red8_b(x0.x * x0.x + x0.y * x0.y);
        float inv = (s > 0.0f) ? rsqrtf(s) : 0.0f;
        xh = pack_h2(x0.x * inv, x0.y * inv);
        #pragma unroll
        for (int mm = 0; mm < M; ++mm) {
            float2 zv = (ids[mm] < n) ? r2[(size_t)ids[mm] * (D / 2) + l]
                                      : make_float2(0.f, 0.f);
            float s2 = red8_b(zv.x * zv.x + zv.y * zv.y);
            float i2 = (s2 > 0.0f) ? rsqrtf(s2) : 0.0f;
            z[mm] = __builtin_bit_cast(u32, pack_h2(zv.x * i2, zv.y * i2));
        }
    }

    const h2 kEighth = pack_h2(0.125f, 0.125f);
    h2 u = xh;
    #pragma unroll
    for (int mm = 0; mm < M; ++mm)
        u = __builtin_bit_cast(h2, z[mm]) * kEighth + u;
    if (max_iter > 1) {
        float s = red8_b(dot2(__builtin_bit_cast(u32, u), u));
        float inv = (s > 0.0f) ? rsqrtf(s) : 0.0f;
        u = u * pack_h2(inv, inv);
    }

    for (int it = 1; it < max_iter; ++it) {
        #pragma unroll
        for (int mm = 0; mm < M; mm += 4) {
            float p0 = dot2(z[mm + 0], u);
            float p1 = dot2(z[mm + 1], u);
            float p2 = dot2(z[mm + 2], u);
            float p3 = dot2(z[mm + 3], u);
            float q0 = 0.f, q1 = 0.f, q2 = 0.f, q3 = 0.f;
            RED8_X8(p0, p1, p2, p3, q0, q1, q2, q3);
            if ((l & 7) == 0) {
                p_lds[wv][mm + 0][myk] = p0;
                p_lds[wv][mm + 1][myk] = p1;
                p_lds[wv][mm + 2][myk] = p2;
                p_lds[wv][mm + 3][myk] = p3;
            }
        }
        __builtin_amdgcn_wave_barrier();

        #pragma unroll
        for (int base = 0; base < M; base += 8) {
            int mm = base + (l >> 3);
            int mc = (mm < M) ? mm : (M - 1);
            float e = __expf(p_lds[wv][mc][l & 7]);
            float S = red8_b(e);
            float w = e * __builtin_amdgcn_rcpf(S);
            w_lds[wv][mc][l & 7] = __builtin_bit_cast(u32, pack_h2(w, w));
        }
        __builtin_amdgcn_wave_barrier();

        h2 unew = xh;
        #pragma unroll
        for (int mm = 0; mm < M; ++mm) {
            h2 w2 = __builtin_bit_cast(h2, w_lds[wv][mm][myk]);
            unew = __builtin_bit_cast(h2, z[mm]) * w2 + unew;
        }
        u = unew;
        if (it < max_iter - 1) {
            float s = red8_b(dot2(__builtin_bit_cast(u32, u), u));
            float inv = (s > 0.0f) ? rsqrtf(s) : 0.0f;
            u = u * pack_h2(inv, inv);
        }
        __builtin_amdgcn_wave_barrier();
    }

    float2* o2 = (float2*)out;
    o2[(size_t)node * (D / 2) + l] = make_float2((float)u.x, (float)u.y);
}

extern "C" void kernel_launch(void* const* d_in, const int* in_sizes, int n_in,
                              void* d_out, int out_size, void* d_ws, size_t ws_size,
                              hipStream_t stream) {
    const float* in  = (const float*)d_in[0];
    const int*   nbr = (const int*)d_in[1];
    const int*   mit = (const int*)d_in[2];
    float*       out = (float*)d_out;

    const int n     = in_sizes[0] / D;    // 50000
    const int total = n * D;

    if (ws_size >= (size_t)(total + D) * sizeof(_Float16)) {
        _Float16* tab = (_Float16*)d_ws;
        prenorm_kernel<<<(total + D + 255) / 256, 256, 0, stream>>>(in, tab, total);
        routing2_kernel<<<(n + 7) / 8, 256, 0, stream>>>(tab, nbr, mit, out, n);
    } else {
        routing1_raw_kernel<<<(n + 3) / 4, 256, 0, stream>>>(in, nbr, mit, out, n);
    }
}

// Round 13
// 49.795 us; speedup vs baseline: 1.1275x; 1.1275x over previous
//
#include <hip/hip_runtime.h>

// RoutingLayer: capsule routing on MI355X (gfx950).
// n = 50000 nodes, D=128 = K=8 capsules x dd=16, M=20 neighbors, max_iter=3.
// Round 13 = round 11 routing kernel BYTE-IDENTICAL (verified, 44 us) +
// vectorized prenorm: 1 thread per dim-PAIR (float2 load 8B/lane, packed-u32
// f16 store), capsule reduce via red8_b over the 8-lane group (primitive
// HW-proven by r10/r11's u-normalization). Halves prenorm inst/thread count.
// Ledger: r6-r9 4-node layout = wrong answers; r12 2-node ILP = regression;
// r11 structure is the verified optimum.

#define D   128
#define K   8
#define DD  16
#define M   20

typedef _Float16 h2 __attribute__((ext_vector_type(2)));
typedef unsigned int u32;

__device__ __forceinline__ h2 pack_h2(float a, float b) {
    return __builtin_bit_cast(h2, __builtin_amdgcn_cvt_pkrtz(a, b));
}

// builtin (compiler-managed hazards) DPP add
#define DPPADD(x, ctrl) ((x) + __int_as_float(__builtin_amdgcn_update_dpp( \
        0, __float_as_int(x), (ctrl), 0xF, 0xF, false)))

__device__ __forceinline__ float red8_b(float x) {    // sum over 8-lane group
    x = DPPADD(x, 0xB1); x = DPPADD(x, 0x4E); x = DPPADD(x, 0x141);
    return x;
}

// 4 independent 8-lane sum reductions, 1 inst per DPP add (r5/r10/r11-proven).
#define RED8_X4(a, b, c, d) \
  asm volatile( \
    "s_nop 1\n\t" \
    "v_add_f32_dpp %0, %0, %0 quad_perm:[1,0,3,2] row_mask:0xf bank_mask:0xf\n\t" \
    "v_add_f32_dpp %1, %1, %1 quad_perm:[1,0,3,2] row_mask:0xf bank_mask:0xf\n\t" \
    "v_add_f32_dpp %2, %2, %2 quad_perm:[1,0,3,2] row_mask:0xf bank_mask:0xf\n\t" \
    "v_add_f32_dpp %3, %3, %3 quad_perm:[1,0,3,2] row_mask:0xf bank_mask:0xf\n\t" \
    "v_add_f32_dpp %0, %0, %0 quad_perm:[2,3,0,1] row_mask:0xf bank_mask:0xf\n\t" \
    "v_add_f32_dpp %1, %1, %1 quad_perm:[2,3,0,1] row_mask:0xf bank_mask:0xf\n\t" \
    "v_add_f32_dpp %2, %2, %2 quad_perm:[2,3,0,1] row_mask:0xf bank_mask:0xf\n\t" \
    "v_add_f32_dpp %3, %3, %3 quad_perm:[2,3,0,1] row_mask:0xf bank_mask:0xf\n\t" \
    "v_add_f32_dpp %0, %0, %0 row_half_mirror row_mask:0xf bank_mask:0xf\n\t" \
    "v_add_f32_dpp %1, %1, %1 row_half_mirror row_mask:0xf bank_mask:0xf\n\t" \
    "v_add_f32_dpp %2, %2, %2 row_half_mirror row_mask:0xf bank_mask:0xf\n\t" \
    "v_add_f32_dpp %3, %3, %3 row_half_mirror row_mask:0xf bank_mask:0xf" \
    : "+v"(a), "+v"(b), "+v"(c), "+v"(d))

__device__ __forceinline__ float dot2(u32 za, h2 ub) {
#if __has_builtin(__builtin_amdgcn_fdot2)
    return __builtin_amdgcn_fdot2(__builtin_bit_cast(h2, za), ub, 0.0f, false);
#else
    h2 ah = __builtin_bit_cast(h2, za);
    return fmaf((float)ah.x, (float)ub.x, (float)ah.y * (float)ub.y);
#endif
}

// Vectorized per-capsule L2 normalize into packed-f16 table.
// One thread per dim-pair: float2 load (8B/lane), red8_b capsule reduce
// (8 lanes x 2 dims = 16-dim capsule), one u32 store. Pad row (64 pairs of
// zeros) appended at [totalPairs, totalPairs+64).
__global__ __launch_bounds__(256) void prenorm2_kernel(const float* __restrict__ in,
                                                       u32* __restrict__ tab,
                                                       int totalPairs) {
    int i = blockIdx.x * 256 + threadIdx.x;          // pair index
    float2 v = make_float2(0.0f, 0.0f);
    if (i < totalPairs) v = ((const float2*)in)[i];  // totalPairs % 8 == 0:
                                                     // no group straddles bound
    float ss = red8_b(v.x * v.x + v.y * v.y);
    float inv = (ss > 0.0f) ? rsqrtf(ss) : 0.0f;     // zero row -> 0 (ref 0/eps)
    if (i < totalPairs + D / 2)
        tab[i] = __builtin_bit_cast(u32, pack_h2(v.x * inv, v.y * inv));
}

template<bool PRE>
__global__ __launch_bounds__(256) void routing_kernel(
    const _Float16* __restrict__ tab,  // PRE: [(n+1)*128] normalized fp16, row n = 0
    const float*    __restrict__ raw,  // !PRE: raw fp32 input
    const int*      __restrict__ nbr,  // [n*20]
    const int*      __restrict__ maxit_p,
    float*          __restrict__ out,  // [n,128] fp32
    int n)
{
    const int t  = threadIdx.x;
    const int wv = t >> 6;                 // wave slot in block
    const int l  = t & 63;                 // lane; owns dims (2l, 2l+1)
    const int node = blockIdx.x * 4 + wv;
    const int myk  = l >> 3;               // capsule 0..7 (8 lanes each)
    if (node >= n) return;
    const int max_iter = maxit_p[0];
    const int nodeu = __builtin_amdgcn_readfirstlane(node);

    __shared__ float p_lds[4][M][K];       // logits (f32)
    __shared__ u32   w_lds[4][M][K];       // packed h2{w,w} weights

    // neighbor ids via scalar pipe (uniform address -> s_load)
    int ids[M];
    {
        const int* nrow = nbr + nodeu * M;
        #pragma unroll
        for (int mm = 0; mm < M; ++mm) ids[mm] = nrow[mm] + nodeu * 5;  // in [0,n]
    }

    // own x + gathered z rows, packed f16 pairs
    u32 z[M];
    h2  xh;                                // own normalized x, packed f16
    if (PRE) {
        const u32* t32 = (const u32*)tab;
        xh = __builtin_bit_cast(h2, t32[(size_t)nodeu * (D / 2) + l]);
        #pragma unroll
        for (int mm = 0; mm < M; ++mm)
            z[mm] = t32[(size_t)ids[mm] * (D / 2) + l];   // row n is zeros
    } else {
        const float2* r2 = (const float2*)raw;
        float2 x0 = r2[(size_t)nodeu * (D / 2) + l];
        float s = red8_b(x0.x * x0.x + x0.y * x0.y);
        float inv = (s > 0.0f) ? rsqrtf(s) : 0.0f;
        xh = pack_h2(x0.x * inv, x0.y * inv);
        #pragma unroll
        for (int mm = 0; mm < M; ++mm) {
            float2 zv = (ids[mm] < n) ? r2[(size_t)ids[mm] * (D / 2) + l]
                                      : make_float2(0.f, 0.f);
            float s2 = red8_b(zv.x * zv.x + zv.y * zv.y);
            float i2 = (s2 > 0.0f) ? rsqrtf(s2) : 0.0f;
            z[mm] = __builtin_bit_cast(u32, pack_h2(zv.x * i2, zv.y * i2));
        }
    }

    // ---- iteration 0: p = softmax(0) = 1/K; u = x + 0.125 * sum_m z ----
    const h2 kEighth = pack_h2(0.125f, 0.125f);
    h2 u = xh;
    #pragma unroll
    for (int mm = 0; mm < M; ++mm)
        u = __builtin_bit_cast(h2, z[mm]) * kEighth + u;   // v_pk_fma_f16
    if (max_iter > 1) {
        float s = red8_b(dot2(__builtin_bit_cast(u32, u), u));  // sum u^2 over capsule
        float inv = (s > 0.0f) ? rsqrtf(s) : 0.0f;
        h2 invh = pack_h2(inv, inv);
        u = u * invh;                                      // v_pk_mul_f16
    }

    // ---- iterations 1..max_iter-1 (intra-wave only) ----
    for (int it = 1; it < max_iter; ++it) {
        // phase 1: capsule dots -> p_lds (r5/r10-proven)
        #pragma unroll
        for (int mm = 0; mm < M; mm += 4) {
            float p0 = dot2(z[mm + 0], u);
            float p1 = dot2(z[mm + 1], u);
            float p2 = dot2(z[mm + 2], u);
            float p3 = dot2(z[mm + 3], u);
            RED8_X4(p0, p1, p2, p3);             // all 8 lanes hold each sum
            if ((l & 7) == 0) {
                p_lds[wv][mm + 0][myk] = p0;
                p_lds[wv][mm + 1][myk] = p1;
                p_lds[wv][mm + 2][myk] = p2;
                p_lds[wv][mm + 3][myk] = p3;
            }
        }
        __builtin_amdgcn_wave_barrier();

        // phase 2: lane-parallel softmax (r10-proven), storing packed h2{w,w}.
        // Lane l handles (m = base + (l>>3), k = l&7); 3 passes; no max-sub
        // (|p|<=1 for unit vectors); S via red8_b; w = e * rcp(S).
        #pragma unroll
        for (int base = 0; base < M; base += 8) {
            int mm = base + (l >> 3);
            int mc = (mm < M) ? mm : (M - 1);          // clamp keeps all lanes live
            float e = __expf(p_lds[wv][mc][l & 7]);
            float S = red8_b(e);                        // sum over k within 8-group
            float w = e * __builtin_amdgcn_rcpf(S);
            if (mm < M)
                w_lds[wv][mm][l & 7] = __builtin_bit_cast(u32, pack_h2(w, w));
        }
        __builtin_amdgcn_wave_barrier();

        // phase 3: PV accumulate, packed f16 (1 v_pk_fma_f16 per m)
        h2 unew = xh;
        #pragma unroll
        for (int mm = 0; mm < M; ++mm) {
            h2 w2 = __builtin_bit_cast(h2, w_lds[wv][mm][myk]);
            unew = __builtin_bit_cast(h2, z[mm]) * w2 + unew;
        }
        u = unew;
        if (it < max_iter - 1) {
            float s = red8_b(dot2(__builtin_bit_cast(u32, u), u));
            float inv = (s > 0.0f) ? rsqrtf(s) : 0.0f;
            h2 invh = pack_h2(inv, inv);
            u = u * invh;
        }
        __builtin_amdgcn_wave_barrier();           // keep next p-writes behind w-reads
    }

    // ---- store: unpack h2 -> f32 pair, coalesced float2 ----
    float2* o2 = (float2*)out;
    o2[(size_t)node * (D / 2) + l] = make_float2((float)u.x, (float)u.y);
}

extern "C" void kernel_launch(void* const* d_in, const int* in_sizes, int n_in,
                              void* d_out, int out_size, void* d_ws, size_t ws_size,
                              hipStream_t stream) {
    const float* in  = (const float*)d_in[0];
    const int*   nbr = (const int*)d_in[1];
    const int*   mit = (const int*)d_in[2];
    float*       out = (float*)d_out;

    const int n     = in_sizes[0] / D;    // 50000
    const int total = n * D;
    const int nblk  = (n + 3) / 4;

    if (ws_size >= (size_t)(total + D) * sizeof(_Float16)) {
        _Float16* tab = (_Float16*)d_ws;
        const int totalPairs = total / 2;                 // 3,200,000 (mult of 8)
        const int tblk = (totalPairs + D / 2 + 255) / 256;
        prenorm2_kernel<<<tblk, 256, 0, stream>>>(in, (u32*)tab, totalPairs);
        routing_kernel<true><<<nblk, 256, 0, stream>>>(tab, nullptr, nbr, mit, out, n);
    } else {
        routing_kernel<false><<<nblk, 256, 0, stream>>>(nullptr, in, nbr, mit, out, n);
    }
}